// Round 4
// baseline (313.817 us; speedup 1.0000x reference)
//
#include <hip/hip_runtime.h>
#include <cstdint>
#include <cstddef>

#define NB    32          // batches
#define SEQ   1024        // sequence length
#define DIN   256
#define HID   512
#define MTOT  32768       // NB*SEQ

typedef _Float16 half_t;
typedef _Float16 half8  __attribute__((ext_vector_type(8)));
typedef _Float16 half4v __attribute__((ext_vector_type(4)));
typedef float    f32x4  __attribute__((ext_vector_type(4)));

typedef __attribute__((address_space(1))) const void* gas_ptr;
typedef __attribute__((address_space(3))) void*       las_ptr;

// ---------------- merged f32 -> f16 conversions ----------------
// blocks [0,8192): h (2M f32x4 chunks); [8192,8704): 4 weights (128 blocks each);
// block 8704: biases.
__global__ void cvt_all(const float* __restrict__ h,
                        const float* __restrict__ Wv, const float* __restrict__ Wk,
                        const float* __restrict__ Wq, const float* __restrict__ Wo,
                        const float* __restrict__ bv, const float* __restrict__ bk,
                        const float* __restrict__ bq,
                        half_t* __restrict__ h16, half_t* __restrict__ W16,
                        half_t* __restrict__ Wo16, float* __restrict__ biasq) {
    int b = blockIdx.x;
    if (b < 8192) {
        int i = b * 256 + threadIdx.x;
        f32x4 v = ((const f32x4*)h)[i];
        half4v o;
        o[0] = (half_t)v[0]; o[1] = (half_t)v[1]; o[2] = (half_t)v[2]; o[3] = (half_t)v[3];
        ((half4v*)h16)[i] = o;
    } else if (b < 8704) {
        int w = (b - 8192) >> 7;
        int i = ((b - 8192) & 127) * 256 + threadIdx.x;
        const float* s = w == 0 ? Wv : w == 1 ? Wk : w == 2 ? Wq : Wo;
        half_t*      d = w < 3 ? W16 + (size_t)w * HID * DIN : Wo16;
        f32x4 v = ((const f32x4*)s)[i];
        half4v o;
        o[0] = (half_t)v[0]; o[1] = (half_t)v[1]; o[2] = (half_t)v[2]; o[3] = (half_t)v[3];
        ((half4v*)d)[i] = o;
    } else {
        for (int i = threadIdx.x; i < HID; i += 256) {
            biasq[i]           = bv[i];
            biasq[HID + i]     = bk[i];
            biasq[2 * HID + i] = bq[i];
        }
    }
}

// ---------------- generic GEMM (projections), 128x128 tile ----------------
// C[m][n] = sum_k A[m][k] * B[n][k]
// MODE 0: QKV proj (unswapped). bias+relu, f16. z=0 -> vT[b][h][m] via out2; z=1,2 row-major.
// MODE 3: out proj (operand-swapped). f32 out, bias+relu, vectorized f32x4 stores.
template<int MODE>
__global__ __launch_bounds__(256, 2) void gemm_k(
    const half_t* __restrict__ A, long lda, long a_bs,
    const half_t* __restrict__ Bw, long ldb, long b_bs,
    void* __restrict__ Out, long ldo, long o_bs,
    const float* __restrict__ bias,
    int Kdim, half_t* __restrict__ out2)
{
    __shared__ alignas(16) half_t As[128 * 32];
    __shared__ alignas(16) half_t Bs[128 * 32];

    const int t    = threadIdx.x;
    const int lane = t & 63;
    const int wave = t >> 6;
    const int wm   = wave >> 1;
    const int wn   = wave & 1;
    const int lanen = lane & 15;
    const int quad  = lane >> 4;
    const int z     = blockIdx.z;
    const long m0 = (long)blockIdx.x * 128;
    const long n0 = (long)blockIdx.y * 128;

    const half_t* Ab = A  + (long)z * a_bs;
    const half_t* Bb = Bw + (long)z * b_bs;

    f32x4 acc[4][4];
#pragma unroll
    for (int i = 0; i < 4; i++)
#pragma unroll
        for (int j = 0; j < 4; j++)
            acc[i][j] = f32x4{0.f, 0.f, 0.f, 0.f};

    const int c0 = t, c1 = t + 256;
    const int r0 = c0 >> 2, kc0 = c0 & 3;
    const int r1 = c1 >> 2, kc1 = c1 & 3;

    const half_t* gA0 = Ab + (m0 + r0) * lda + kc0 * 8;
    const half_t* gA1 = Ab + (m0 + r1) * lda + kc1 * 8;
    const half_t* gB0 = Bb + (n0 + r0) * ldb + kc0 * 8;
    const half_t* gB1 = Bb + (n0 + r1) * ldb + kc1 * 8;
    half_t* lA0 = &As[c0 * 8];
    half_t* lA1 = &As[c1 * 8];
    half_t* lB0 = &Bs[c0 * 8];
    half_t* lB1 = &Bs[c1 * 8];

    int aoff[4], boff[4];
#pragma unroll
    for (int i = 0; i < 4; i++) aoff[i] = (wm * 64 + i * 16 + lanen) * 32 + quad * 8;
#pragma unroll
    for (int j = 0; j < 4; j++) boff[j] = (wn * 64 + j * 16 + lanen) * 32 + quad * 8;

    for (int k0 = 0; k0 < Kdim; k0 += 32) {
        __builtin_amdgcn_global_load_lds((gas_ptr)(gA0 + k0), (las_ptr)lA0, 16, 0, 0);
        __builtin_amdgcn_global_load_lds((gas_ptr)(gA1 + k0), (las_ptr)lA1, 16, 0, 0);
        __builtin_amdgcn_global_load_lds((gas_ptr)(gB0 + k0), (las_ptr)lB0, 16, 0, 0);
        __builtin_amdgcn_global_load_lds((gas_ptr)(gB1 + k0), (las_ptr)lB1, 16, 0, 0);
        __syncthreads();

        half8 af[4], bf[4];
#pragma unroll
        for (int i = 0; i < 4; i++) af[i] = *(const half8*)&As[aoff[i]];
#pragma unroll
        for (int j = 0; j < 4; j++) bf[j] = *(const half8*)&Bs[boff[j]];
#pragma unroll
        for (int i = 0; i < 4; i++)
#pragma unroll
            for (int j = 0; j < 4; j++) {
                if (MODE == 3)
                    acc[i][j] = __builtin_amdgcn_mfma_f32_16x16x32_f16(bf[j], af[i], acc[i][j], 0, 0, 0);
                else
                    acc[i][j] = __builtin_amdgcn_mfma_f32_16x16x32_f16(af[i], bf[j], acc[i][j], 0, 0, 0);
            }
        __syncthreads();
    }

    if (MODE == 0) {
        // C/D layout: col(lane&15) = n, row(quad*4+r) = m
#pragma unroll
        for (int i = 0; i < 4; i++) {
            long mrow = m0 + wm * 64 + i * 16 + quad * 4;
#pragma unroll
            for (int j = 0; j < 4; j++) {
                long gn = n0 + wn * 64 + j * 16 + lanen;
                f32x4 v = acc[i][j];
                float bb = bias[z * HID + gn];
                half_t h0 = (half_t)fmaxf(v[0] + bb, 0.f);
                half_t h1 = (half_t)fmaxf(v[1] + bb, 0.f);
                half_t h2 = (half_t)fmaxf(v[2] + bb, 0.f);
                half_t h3 = (half_t)fmaxf(v[3] + bb, 0.f);
                if (z == 0) {
                    long bidx = mrow >> 10;
                    long pos  = mrow & 1023;
                    half4v pk; pk[0] = h0; pk[1] = h1; pk[2] = h2; pk[3] = h3;
                    *(half4v*)(out2 + ((bidx * HID + gn) << 10) + pos) = pk;
                } else {
                    half_t* o = (half_t*)Out + (long)(z - 1) * o_bs;
                    o[(mrow + 0) * ldo + gn] = h0;
                    o[(mrow + 1) * ldo + gn] = h1;
                    o[(mrow + 2) * ldo + gn] = h2;
                    o[(mrow + 3) * ldo + gn] = h3;
                }
            }
        }
    } else {
        // swapped: col(lane&15) = m, row(quad*4+r) = n -> contiguous output cols
        float* o = (float*)Out;
#pragma unroll
        for (int i = 0; i < 4; i++) {
            long mrow = m0 + wm * 64 + i * 16 + lanen;
#pragma unroll
            for (int j = 0; j < 4; j++) {
                long gn = n0 + wn * 64 + j * 16 + quad * 4;
                f32x4 bb = *(const f32x4*)&bias[gn];
                f32x4 v = acc[i][j];
                f32x4 ov;
#pragma unroll
                for (int r = 0; r < 4; r++) ov[r] = fmaxf(v[r] + bb[r], 0.f);
                *(f32x4*)&o[mrow * ldo + gn] = ov;
            }
        }
    }
}

// ---------------- S = q k^T with fused exp, 128x256 tile, swapped operands ----------------
// acc[i][j] = mfma(bf[j], af[i]) -> lane holds qrow = wm*64+i*16+lanen,
// kcols = wn*128 + j*16 + quad*4 + {0..3}  (contiguous -> half4v stores).
__global__ __launch_bounds__(256, 2) void se_k(
    const half_t* __restrict__ Q, const half_t* __restrict__ K,
    half_t* __restrict__ E, float* __restrict__ Mstat, float* __restrict__ Lstat)
{
    __shared__ alignas(16) half_t As[128 * 32];
    __shared__ alignas(16) half_t Bs[256 * 32];

    const int t    = threadIdx.x;
    const int lane = t & 63;
    const int wave = t >> 6;
    const int wm   = wave >> 1;
    const int wn   = wave & 1;
    const int lanen = lane & 15;
    const int quad  = lane >> 4;
    const int z     = blockIdx.z;
    const long m0 = (long)blockIdx.x * 128;
    const long n0 = (long)blockIdx.y * 256;

    const half_t* Ab = Q + (long)z * SEQ * HID;
    const half_t* Bb = K + (long)z * SEQ * HID;

    f32x4 acc[4][8];
#pragma unroll
    for (int i = 0; i < 4; i++)
#pragma unroll
        for (int j = 0; j < 8; j++)
            acc[i][j] = f32x4{0.f, 0.f, 0.f, 0.f};

    const half_t* gA[2]; half_t* lA[2];
    const half_t* gB[4]; half_t* lB[4];
#pragma unroll
    for (int s = 0; s < 2; s++) {
        int c = t + 256 * s;
        gA[s] = Ab + (m0 + (c >> 2)) * HID + (c & 3) * 8;
        lA[s] = &As[c * 8];
    }
#pragma unroll
    for (int s = 0; s < 4; s++) {
        int c = t + 256 * s;
        gB[s] = Bb + (n0 + (c >> 2)) * HID + (c & 3) * 8;
        lB[s] = &Bs[c * 8];
    }

    int aoff[4], boff[8];
#pragma unroll
    for (int i = 0; i < 4; i++) aoff[i] = (wm * 64 + i * 16 + lanen) * 32 + quad * 8;
#pragma unroll
    for (int j = 0; j < 8; j++) boff[j] = (wn * 128 + j * 16 + lanen) * 32 + quad * 8;

    for (int k0 = 0; k0 < HID; k0 += 32) {
#pragma unroll
        for (int s = 0; s < 2; s++)
            __builtin_amdgcn_global_load_lds((gas_ptr)(gA[s] + k0), (las_ptr)lA[s], 16, 0, 0);
#pragma unroll
        for (int s = 0; s < 4; s++)
            __builtin_amdgcn_global_load_lds((gas_ptr)(gB[s] + k0), (las_ptr)lB[s], 16, 0, 0);
        __syncthreads();

        half8 af[4], bf[8];
#pragma unroll
        for (int i = 0; i < 4; i++) af[i] = *(const half8*)&As[aoff[i]];
#pragma unroll
        for (int j = 0; j < 8; j++) bf[j] = *(const half8*)&Bs[boff[j]];
#pragma unroll
        for (int i = 0; i < 4; i++)
#pragma unroll
            for (int j = 0; j < 8; j++)
                acc[i][j] = __builtin_amdgcn_mfma_f32_16x16x32_f16(bf[j], af[i], acc[i][j], 0, 0, 0);
        __syncthreads();
    }

    // ---- per-qrow max over this wave's 128 cols (in-lane 32 + cross-quad shfl) ----
    float mf[4];
#pragma unroll
    for (int i = 0; i < 4; i++) {
        float v = acc[i][0][0];
#pragma unroll
        for (int j = 0; j < 8; j++)
#pragma unroll
            for (int r = 0; r < 4; r++) v = fmaxf(v, acc[i][j][r]);
        v = fmaxf(v, __shfl_xor(v, 16, 64));
        v = fmaxf(v, __shfl_xor(v, 32, 64));
        mf[i] = v;
    }

    // ---- exp + row sums + packed E stores ----
    half_t* Eb = E + (long)z * SEQ * SEQ;
    float rs[4] = {0.f, 0.f, 0.f, 0.f};
#pragma unroll
    for (int i = 0; i < 4; i++) {
        long qrow = m0 + wm * 64 + i * 16 + lanen;
#pragma unroll
        for (int j = 0; j < 8; j++) {
            long gn = n0 + wn * 128 + j * 16 + quad * 4;
            half4v hv;
#pragma unroll
            for (int r = 0; r < 4; r++) {
                float e = __expf(acc[i][j][r] - mf[i]);
                rs[i] += e;
                hv[r] = (half_t)e;
            }
            *(half4v*)(Eb + qrow * SEQ + gn) = hv;
        }
    }
#pragma unroll
    for (int i = 0; i < 4; i++) {
        float v = rs[i];
        v += __shfl_xor(v, 16, 64);
        v += __shfl_xor(v, 32, 64);
        rs[i] = v;
    }

    // stats: kb = blockIdx.y*2 + wn; quad==0 lanes write 16 consecutive rows per i
    if (quad == 0) {
        long base = ((long)z * 8 + blockIdx.y * 2 + wn) * SEQ + m0 + wm * 64;
#pragma unroll
        for (int i = 0; i < 4; i++) {
            Mstat[base + i * 16 + lanen] = mf[i];
            Lstat[base + i * 16 + lanen] = rs[i];
        }
    }
}

// ---------------- O = P vT with rescale + normalize, 128x256, swapped operands ----------------
__global__ __launch_bounds__(256, 2) void pv_k(
    const half_t* __restrict__ E, const half_t* __restrict__ vT,
    const float* __restrict__ Mstat, const float* __restrict__ Lstat,
    half_t* __restrict__ O16)
{
    __shared__ alignas(16) half_t As[128 * 32];
    __shared__ alignas(16) half_t Bs[256 * 32];
    __shared__ float scaleS[8][128];
    __shared__ float invS[128];

    const int t    = threadIdx.x;
    const int lane = t & 63;
    const int wave = t >> 6;
    const int wm   = wave >> 1;
    const int wn   = wave & 1;
    const int lanen = lane & 15;
    const int quad  = lane >> 4;
    const int z     = blockIdx.z;
    const long m0 = (long)blockIdx.x * 128;
    const long h0 = (long)blockIdx.y * 256;

    if (t < 128) {
        float mv[8];
        float M = -1e30f;
#pragma unroll
        for (int kb = 0; kb < 8; kb++) {
            mv[kb] = Mstat[((long)z * 8 + kb) * SEQ + m0 + t];
            M = fmaxf(M, mv[kb]);
        }
        float ls = 0.f;
#pragma unroll
        for (int kb = 0; kb < 8; kb++) {
            float sc = __expf(mv[kb] - M);
            scaleS[kb][t] = sc;
            ls += Lstat[((long)z * 8 + kb) * SEQ + m0 + t] * sc;
        }
        invS[t] = 1.f / ls;
    }
    __syncthreads();

    const half_t* Ab = E  + (long)z * SEQ * SEQ;
    const half_t* Bb = vT + (long)z * HID * SEQ;

    f32x4 acc[4][8];
#pragma unroll
    for (int i = 0; i < 4; i++)
#pragma unroll
        for (int j = 0; j < 8; j++)
            acc[i][j] = f32x4{0.f, 0.f, 0.f, 0.f};

    const half_t* gA[2]; half_t* lA[2];
    const half_t* gB[4]; half_t* lB[4];
#pragma unroll
    for (int s = 0; s < 2; s++) {
        int c = t + 256 * s;
        gA[s] = Ab + (m0 + (c >> 2)) * SEQ + (c & 3) * 8;
        lA[s] = &As[c * 8];
    }
#pragma unroll
    for (int s = 0; s < 4; s++) {
        int c = t + 256 * s;
        gB[s] = Bb + (h0 + (c >> 2)) * SEQ + (c & 3) * 8;
        lB[s] = &Bs[c * 8];
    }

    int aoff[4], boff[8];
#pragma unroll
    for (int i = 0; i < 4; i++) aoff[i] = (wm * 64 + i * 16 + lanen) * 32 + quad * 8;
#pragma unroll
    for (int j = 0; j < 8; j++) boff[j] = (wn * 128 + j * 16 + lanen) * 32 + quad * 8;

    for (int k0 = 0; k0 < SEQ; k0 += 32) {
#pragma unroll
        for (int s = 0; s < 2; s++)
            __builtin_amdgcn_global_load_lds((gas_ptr)(gA[s] + k0), (las_ptr)lA[s], 16, 0, 0);
#pragma unroll
        for (int s = 0; s < 4; s++)
            __builtin_amdgcn_global_load_lds((gas_ptr)(gB[s] + k0), (las_ptr)lB[s], 16, 0, 0);
        __syncthreads();

        const int kb = k0 >> 7;
        half8 af[4], bf[8];
#pragma unroll
        for (int i = 0; i < 4; i++) {
            af[i] = *(const half8*)&As[aoff[i]];
            half_t sh = (half_t)scaleS[kb][wm * 64 + i * 16 + lanen];
            af[i] *= sh;   // per-qrow rescale; operand free-dim = lane&15 either slot
        }
#pragma unroll
        for (int j = 0; j < 8; j++) bf[j] = *(const half8*)&Bs[boff[j]];
#pragma unroll
        for (int i = 0; i < 4; i++)
#pragma unroll
            for (int j = 0; j < 8; j++)
                acc[i][j] = __builtin_amdgcn_mfma_f32_16x16x32_f16(bf[j], af[i], acc[i][j], 0, 0, 0);
        __syncthreads();
    }

    // swapped: lane holds qrow = wm*64+i*16+lanen, h-cols = wn*128+j*16+quad*4+{0..3}
    half_t* o = O16 + (long)z * SEQ * HID;
#pragma unroll
    for (int i = 0; i < 4; i++) {
        int qrl = wm * 64 + i * 16 + lanen;
        long qrow = m0 + qrl;
        float inv = invS[qrl];
#pragma unroll
        for (int j = 0; j < 8; j++) {
            long gn = h0 + wn * 128 + j * 16 + quad * 4;
            half4v hv;
#pragma unroll
            for (int r = 0; r < 4; r++) hv[r] = (half_t)(acc[i][j][r] * inv);
            *(half4v*)(o + qrow * HID + gn) = hv;
        }
    }
}

// ---------------- host ----------------
extern "C" void kernel_launch(void* const* d_in, const int* in_sizes, int n_in,
                              void* d_out, int out_size, void* d_ws, size_t ws_size,
                              hipStream_t stream) {
    const float* h  = (const float*)d_in[0];
    const float* Wv = (const float*)d_in[1];
    const float* bv = (const float*)d_in[2];
    const float* Wk = (const float*)d_in[3];
    const float* bk = (const float*)d_in[4];
    const float* Wq = (const float*)d_in[5];
    const float* bq = (const float*)d_in[6];
    const float* Wo = (const float*)d_in[7];
    const float* bo = (const float*)d_in[8];

    uint8_t* ws = (uint8_t*)d_ws;
    size_t off = 0;
    auto alloc = [&](size_t bytes) { size_t o = off; off += (bytes + 255) & ~(size_t)255; return o; };

    half_t* W16   = (half_t*)(ws + alloc((size_t)3 * HID * DIN * 2)); // [Wv][Wk][Wq]
    half_t* Wo16  = (half_t*)(ws + alloc((size_t)DIN * HID * 2));
    float*  biasq = (float*)(ws + alloc((size_t)3 * HID * 4));        // [bv][bk][bq]
    half_t* k16   = (half_t*)(ws + alloc((size_t)MTOT * HID * 2));
    half_t* q16   = (half_t*)(ws + alloc((size_t)MTOT * HID * 2));    // reused as O16 per group
    half_t* vT    = (half_t*)(ws + alloc((size_t)MTOT * HID * 2));    // [b][h][m]
    size_t h16_off = alloc((size_t)MTOT * DIN * 2);
    half_t* h16   = (half_t*)(ws + h16_off);
    half_t* O16 = q16;  // q dead after its group's se_k; O written strictly after

    // E + stats overlap the (dead-after-K1) h16 region onward.
    // GB capped at 16: E chunk = 32 MB -> Infinity-Cache-resident between se_k/pv_k,
    // and pv grid (8*2*16=256 blocks) still fills all CUs.
    size_t s_avail = ws_size > h16_off ? ws_size - h16_off : 0;
    size_t per_batch = (size_t)SEQ * SEQ * 2 + 2 * 8 * SEQ * 4;
    int GB = (int)(s_avail / per_batch);
    if (GB > 16) GB = 16;
    if (GB < 1)  GB = 1;
    half_t* Ebuf  = (half_t*)(ws + h16_off);
    float*  Mstat = (float*)(ws + h16_off + (size_t)GB * SEQ * SEQ * 2);
    float*  Lstat = Mstat + (size_t)GB * 8 * SEQ;

    // K0: merged conversions
    cvt_all<<<dim3(8705), 256, 0, stream>>>(h, Wv, Wk, Wq, Wo, bv, bk, bq,
                                            h16, W16, Wo16, biasq);

    // K1: QKV projections (z: 0=V->vT, 1=K, 2=Q)
    gemm_k<0><<<dim3(MTOT / 128, HID / 128, 3), 256, 0, stream>>>(
        h16, DIN, 0,
        W16, DIN, (long)HID * DIN,
        (void*)k16, HID, (long)MTOT * HID,
        biasq, DIN, vT);

    for (int g0 = 0; g0 < NB; g0 += GB) {
        int gb = NB - g0 < GB ? NB - g0 : GB;
        // K2: E = exp(q k^T - m_loc) + stats  (128x256 tiles)
        se_k<<<dim3(SEQ / 128, SEQ / 256, gb), 256, 0, stream>>>(
            q16 + (size_t)g0 * SEQ * HID,
            k16 + (size_t)g0 * SEQ * HID,
            Ebuf, Mstat, Lstat);
        // K4: O = (scaled E) vT / lsum  (128x256 tiles)
        pv_k<<<dim3(SEQ / 128, HID / 256, gb), 256, 0, stream>>>(
            Ebuf, vT + (size_t)g0 * HID * SEQ,
            Mstat, Lstat,
            O16 + (size_t)g0 * SEQ * HID);
    }

    // K5: out = relu(O Wo^T + bo)  (f32 out, swapped epilogue, f32x4 stores)
    gemm_k<3><<<dim3(MTOT / 128, DIN / 128, 1), 256, 0, stream>>>(
        O16, HID, 0,
        Wo16, HID, 0,
        d_out, DIN, 0,
        bo, HID, nullptr);

    (void)in_sizes; (void)n_in; (void)out_size;
}

// Round 5
// 309.686 us; speedup vs baseline: 1.0133x; 1.0133x over previous
//
#include <hip/hip_runtime.h>
#include <cstdint>
#include <cstddef>

#define NB    32          // batches
#define SEQ   1024        // sequence length
#define DIN   256
#define HID   512
#define MTOT  32768       // NB*SEQ

typedef _Float16 half_t;
typedef _Float16 half8  __attribute__((ext_vector_type(8)));
typedef _Float16 half4v __attribute__((ext_vector_type(4)));
typedef float    f32x4  __attribute__((ext_vector_type(4)));

typedef __attribute__((address_space(1))) const void* gas_ptr;
typedef __attribute__((address_space(3))) void*       las_ptr;

// ---------------- merged f32 -> f16 conversions ----------------
__global__ void cvt_all(const float* __restrict__ h,
                        const float* __restrict__ Wv, const float* __restrict__ Wk,
                        const float* __restrict__ Wq, const float* __restrict__ Wo,
                        const float* __restrict__ bv, const float* __restrict__ bk,
                        const float* __restrict__ bq,
                        half_t* __restrict__ h16, half_t* __restrict__ W16,
                        half_t* __restrict__ Wo16, float* __restrict__ biasq) {
    int b = blockIdx.x;
    if (b < 8192) {
        int i = b * 256 + threadIdx.x;
        f32x4 v = ((const f32x4*)h)[i];
        half4v o;
        o[0] = (half_t)v[0]; o[1] = (half_t)v[1]; o[2] = (half_t)v[2]; o[3] = (half_t)v[3];
        ((half4v*)h16)[i] = o;
    } else if (b < 8704) {
        int w = (b - 8192) >> 7;
        int i = ((b - 8192) & 127) * 256 + threadIdx.x;
        const float* s = w == 0 ? Wv : w == 1 ? Wk : w == 2 ? Wq : Wo;
        half_t*      d = w < 3 ? W16 + (size_t)w * HID * DIN : Wo16;
        f32x4 v = ((const f32x4*)s)[i];
        half4v o;
        o[0] = (half_t)v[0]; o[1] = (half_t)v[1]; o[2] = (half_t)v[2]; o[3] = (half_t)v[3];
        ((half4v*)d)[i] = o;
    } else {
        for (int i = threadIdx.x; i < HID; i += 256) {
            biasq[i]           = bv[i];
            biasq[HID + i]     = bk[i];
            biasq[2 * HID + i] = bq[i];
        }
    }
}

// ---------------- fused QKV projection, 128x256 tile ----------------
// One GEMM: A = h16 [32768][256], B = W16 = [Wv;Wk;Wq] as [1536][256].
// n-tile (256 wide) lies wholly in V (n0<512), K ([512,1024)), or Q ([1024,1536)).
// V: unswapped mfma -> m-contiguous regs -> packed vT[b][h][m] stores.
// K/Q: swapped mfma -> n-contiguous regs -> packed row-major [m][h] stores.
__global__ __launch_bounds__(256, 2) void qkv_k(
    const half_t* __restrict__ A, const half_t* __restrict__ Bw,
    const float* __restrict__ biasq,
    half_t* __restrict__ k16, half_t* __restrict__ q16, half_t* __restrict__ vT)
{
    __shared__ alignas(16) half_t As[128 * 32];
    __shared__ alignas(16) half_t Bs[256 * 32];

    const int t    = threadIdx.x;
    const int lane = t & 63;
    const int wave = t >> 6;
    const int wm   = wave >> 1;
    const int wn   = wave & 1;
    const int lanen = lane & 15;
    const int quad  = lane >> 4;
    const long m0 = (long)blockIdx.x * 128;
    const long n0 = (long)blockIdx.y * 256;

    const half_t* gA[2]; half_t* lA[2];
    const half_t* gB[4]; half_t* lB[4];
#pragma unroll
    for (int s = 0; s < 2; s++) {
        int c = t + 256 * s;
        gA[s] = A + (m0 + (c >> 2)) * DIN + (c & 3) * 8;
        lA[s] = &As[c * 8];
    }
#pragma unroll
    for (int s = 0; s < 4; s++) {
        int c = t + 256 * s;
        gB[s] = Bw + (n0 + (c >> 2)) * DIN + (c & 3) * 8;
        lB[s] = &Bs[c * 8];
    }

    int aoff[4], boff[8];
#pragma unroll
    for (int i = 0; i < 4; i++) aoff[i] = (wm * 64 + i * 16 + lanen) * 32 + quad * 8;
#pragma unroll
    for (int j = 0; j < 8; j++) boff[j] = (wn * 128 + j * 16 + lanen) * 32 + quad * 8;

    f32x4 acc[4][8];
#pragma unroll
    for (int i = 0; i < 4; i++)
#pragma unroll
        for (int j = 0; j < 8; j++)
            acc[i][j] = f32x4{0.f, 0.f, 0.f, 0.f};

    if (n0 < 512) {
        // ---------- V path: unswapped ----------
        for (int k0 = 0; k0 < DIN; k0 += 32) {
#pragma unroll
            for (int s = 0; s < 2; s++)
                __builtin_amdgcn_global_load_lds((gas_ptr)(gA[s] + k0), (las_ptr)lA[s], 16, 0, 0);
#pragma unroll
            for (int s = 0; s < 4; s++)
                __builtin_amdgcn_global_load_lds((gas_ptr)(gB[s] + k0), (las_ptr)lB[s], 16, 0, 0);
            __syncthreads();
            half8 af[4], bf[8];
#pragma unroll
            for (int i = 0; i < 4; i++) af[i] = *(const half8*)&As[aoff[i]];
#pragma unroll
            for (int j = 0; j < 8; j++) bf[j] = *(const half8*)&Bs[boff[j]];
#pragma unroll
            for (int i = 0; i < 4; i++)
#pragma unroll
                for (int j = 0; j < 8; j++)
                    acc[i][j] = __builtin_amdgcn_mfma_f32_16x16x32_f16(af[i], bf[j], acc[i][j], 0, 0, 0);
            __syncthreads();
        }
        // epilogue: lane col = n (lanen), rows = quad*4+r (m-contiguous) -> vT stores
#pragma unroll
        for (int i = 0; i < 4; i++) {
            long mrow = m0 + wm * 64 + i * 16 + quad * 4;
            long bidx = mrow >> 10;
            long pos  = mrow & 1023;
#pragma unroll
            for (int j = 0; j < 8; j++) {
                long gn = n0 + wn * 128 + j * 16 + lanen;
                float bb = biasq[gn];
                f32x4 v = acc[i][j];
                half4v pk;
#pragma unroll
                for (int r = 0; r < 4; r++) pk[r] = (half_t)fmaxf(v[r] + bb, 0.f);
                *(half4v*)(vT + ((bidx * HID + gn) << 10) + pos) = pk;
            }
        }
    } else {
        // ---------- K/Q path: swapped ----------
        for (int k0 = 0; k0 < DIN; k0 += 32) {
#pragma unroll
            for (int s = 0; s < 2; s++)
                __builtin_amdgcn_global_load_lds((gas_ptr)(gA[s] + k0), (las_ptr)lA[s], 16, 0, 0);
#pragma unroll
            for (int s = 0; s < 4; s++)
                __builtin_amdgcn_global_load_lds((gas_ptr)(gB[s] + k0), (las_ptr)lB[s], 16, 0, 0);
            __syncthreads();
            half8 af[4], bf[8];
#pragma unroll
            for (int i = 0; i < 4; i++) af[i] = *(const half8*)&As[aoff[i]];
#pragma unroll
            for (int j = 0; j < 8; j++) bf[j] = *(const half8*)&Bs[boff[j]];
#pragma unroll
            for (int i = 0; i < 4; i++)
#pragma unroll
                for (int j = 0; j < 8; j++)
                    acc[i][j] = __builtin_amdgcn_mfma_f32_16x16x32_f16(bf[j], af[i], acc[i][j], 0, 0, 0);
            __syncthreads();
        }
        // epilogue: lane row m = lanen-based, cols = quad*4+r (n-contiguous) -> packed stores
        half_t* dst   = n0 < 1024 ? k16 : q16;
        long    hbase = n0 < 1024 ? n0 - 512 : n0 - 1024;
#pragma unroll
        for (int i = 0; i < 4; i++) {
            long mrow = m0 + wm * 64 + i * 16 + lanen;
#pragma unroll
            for (int j = 0; j < 8; j++) {
                long gn = n0 + wn * 128 + j * 16 + quad * 4;
                f32x4 bb = *(const f32x4*)&biasq[gn];
                f32x4 v = acc[i][j];
                half4v pk;
#pragma unroll
                for (int r = 0; r < 4; r++) pk[r] = (half_t)fmaxf(v[r] + bb[r], 0.f);
                *(half4v*)(dst + mrow * HID + (hbase + wn * 128 + j * 16 + quad * 4)) = pk;
            }
        }
    }
}

// ---------------- S = q k^T with fused exp, 128x256 tile, swapped operands ----------------
__global__ __launch_bounds__(256, 2) void se_k(
    const half_t* __restrict__ Q, const half_t* __restrict__ K,
    half_t* __restrict__ E, float* __restrict__ Mstat, float* __restrict__ Lstat)
{
    __shared__ alignas(16) half_t As[128 * 32];
    __shared__ alignas(16) half_t Bs[256 * 32];

    const int t    = threadIdx.x;
    const int lane = t & 63;
    const int wave = t >> 6;
    const int wm   = wave >> 1;
    const int wn   = wave & 1;
    const int lanen = lane & 15;
    const int quad  = lane >> 4;
    const int z     = blockIdx.z;
    const long m0 = (long)blockIdx.x * 128;
    const long n0 = (long)blockIdx.y * 256;

    const half_t* Ab = Q + (long)z * SEQ * HID;
    const half_t* Bb = K + (long)z * SEQ * HID;

    f32x4 acc[4][8];
#pragma unroll
    for (int i = 0; i < 4; i++)
#pragma unroll
        for (int j = 0; j < 8; j++)
            acc[i][j] = f32x4{0.f, 0.f, 0.f, 0.f};

    const half_t* gA[2]; half_t* lA[2];
    const half_t* gB[4]; half_t* lB[4];
#pragma unroll
    for (int s = 0; s < 2; s++) {
        int c = t + 256 * s;
        gA[s] = Ab + (m0 + (c >> 2)) * HID + (c & 3) * 8;
        lA[s] = &As[c * 8];
    }
#pragma unroll
    for (int s = 0; s < 4; s++) {
        int c = t + 256 * s;
        gB[s] = Bb + (n0 + (c >> 2)) * HID + (c & 3) * 8;
        lB[s] = &Bs[c * 8];
    }

    int aoff[4], boff[8];
#pragma unroll
    for (int i = 0; i < 4; i++) aoff[i] = (wm * 64 + i * 16 + lanen) * 32 + quad * 8;
#pragma unroll
    for (int j = 0; j < 8; j++) boff[j] = (wn * 128 + j * 16 + lanen) * 32 + quad * 8;

    for (int k0 = 0; k0 < HID; k0 += 32) {
#pragma unroll
        for (int s = 0; s < 2; s++)
            __builtin_amdgcn_global_load_lds((gas_ptr)(gA[s] + k0), (las_ptr)lA[s], 16, 0, 0);
#pragma unroll
        for (int s = 0; s < 4; s++)
            __builtin_amdgcn_global_load_lds((gas_ptr)(gB[s] + k0), (las_ptr)lB[s], 16, 0, 0);
        __syncthreads();

        half8 af[4], bf[8];
#pragma unroll
        for (int i = 0; i < 4; i++) af[i] = *(const half8*)&As[aoff[i]];
#pragma unroll
        for (int j = 0; j < 8; j++) bf[j] = *(const half8*)&Bs[boff[j]];
#pragma unroll
        for (int i = 0; i < 4; i++)
#pragma unroll
            for (int j = 0; j < 8; j++)
                acc[i][j] = __builtin_amdgcn_mfma_f32_16x16x32_f16(bf[j], af[i], acc[i][j], 0, 0, 0);
        __syncthreads();
    }

    float mf[4];
#pragma unroll
    for (int i = 0; i < 4; i++) {
        float v = acc[i][0][0];
#pragma unroll
        for (int j = 0; j < 8; j++)
#pragma unroll
            for (int r = 0; r < 4; r++) v = fmaxf(v, acc[i][j][r]);
        v = fmaxf(v, __shfl_xor(v, 16, 64));
        v = fmaxf(v, __shfl_xor(v, 32, 64));
        mf[i] = v;
    }

    half_t* Eb = E + (long)z * SEQ * SEQ;
    float rs[4] = {0.f, 0.f, 0.f, 0.f};
#pragma unroll
    for (int i = 0; i < 4; i++) {
        long qrow = m0 + wm * 64 + i * 16 + lanen;
#pragma unroll
        for (int j = 0; j < 8; j++) {
            long gn = n0 + wn * 128 + j * 16 + quad * 4;
            half4v hv;
#pragma unroll
            for (int r = 0; r < 4; r++) {
                float e = __expf(acc[i][j][r] - mf[i]);
                rs[i] += e;
                hv[r] = (half_t)e;
            }
            *(half4v*)(Eb + qrow * SEQ + gn) = hv;
        }
    }
#pragma unroll
    for (int i = 0; i < 4; i++) {
        float v = rs[i];
        v += __shfl_xor(v, 16, 64);
        v += __shfl_xor(v, 32, 64);
        rs[i] = v;
    }

    if (quad == 0) {
        long base = ((long)z * 8 + blockIdx.y * 2 + wn) * SEQ + m0 + wm * 64;
#pragma unroll
        for (int i = 0; i < 4; i++) {
            Mstat[base + i * 16 + lanen] = mf[i];
            Lstat[base + i * 16 + lanen] = rs[i];
        }
    }
}

// ---------------- O = P vT with rescale + normalize, 128x256, swapped operands ----------------
__global__ __launch_bounds__(256, 2) void pv_k(
    const half_t* __restrict__ E, const half_t* __restrict__ vT,
    const float* __restrict__ Mstat, const float* __restrict__ Lstat,
    half_t* __restrict__ O16)
{
    __shared__ alignas(16) half_t As[128 * 32];
    __shared__ alignas(16) half_t Bs[256 * 32];
    __shared__ float scaleS[8][128];
    __shared__ float invS[128];

    const int t    = threadIdx.x;
    const int lane = t & 63;
    const int wave = t >> 6;
    const int wm   = wave >> 1;
    const int wn   = wave & 1;
    const int lanen = lane & 15;
    const int quad  = lane >> 4;
    const int z     = blockIdx.z;
    const long m0 = (long)blockIdx.x * 128;
    const long h0 = (long)blockIdx.y * 256;

    if (t < 128) {
        float mv[8];
        float M = -1e30f;
#pragma unroll
        for (int kb = 0; kb < 8; kb++) {
            mv[kb] = Mstat[((long)z * 8 + kb) * SEQ + m0 + t];
            M = fmaxf(M, mv[kb]);
        }
        float ls = 0.f;
#pragma unroll
        for (int kb = 0; kb < 8; kb++) {
            float sc = __expf(mv[kb] - M);
            scaleS[kb][t] = sc;
            ls += Lstat[((long)z * 8 + kb) * SEQ + m0 + t] * sc;
        }
        invS[t] = 1.f / ls;
    }
    __syncthreads();

    const half_t* Ab = E  + (long)z * SEQ * SEQ;
    const half_t* Bb = vT + (long)z * HID * SEQ;

    f32x4 acc[4][8];
#pragma unroll
    for (int i = 0; i < 4; i++)
#pragma unroll
        for (int j = 0; j < 8; j++)
            acc[i][j] = f32x4{0.f, 0.f, 0.f, 0.f};

    const half_t* gA[2]; half_t* lA[2];
    const half_t* gB[4]; half_t* lB[4];
#pragma unroll
    for (int s = 0; s < 2; s++) {
        int c = t + 256 * s;
        gA[s] = Ab + (m0 + (c >> 2)) * SEQ + (c & 3) * 8;
        lA[s] = &As[c * 8];
    }
#pragma unroll
    for (int s = 0; s < 4; s++) {
        int c = t + 256 * s;
        gB[s] = Bb + (h0 + (c >> 2)) * SEQ + (c & 3) * 8;
        lB[s] = &Bs[c * 8];
    }

    int aoff[4], boff[8];
#pragma unroll
    for (int i = 0; i < 4; i++) aoff[i] = (wm * 64 + i * 16 + lanen) * 32 + quad * 8;
#pragma unroll
    for (int j = 0; j < 8; j++) boff[j] = (wn * 128 + j * 16 + lanen) * 32 + quad * 8;

    for (int k0 = 0; k0 < SEQ; k0 += 32) {
#pragma unroll
        for (int s = 0; s < 2; s++)
            __builtin_amdgcn_global_load_lds((gas_ptr)(gA[s] + k0), (las_ptr)lA[s], 16, 0, 0);
#pragma unroll
        for (int s = 0; s < 4; s++)
            __builtin_amdgcn_global_load_lds((gas_ptr)(gB[s] + k0), (las_ptr)lB[s], 16, 0, 0);
        __syncthreads();

        const int kb = k0 >> 7;
        half8 af[4], bf[8];
#pragma unroll
        for (int i = 0; i < 4; i++) {
            af[i] = *(const half8*)&As[aoff[i]];
            half_t sh = (half_t)scaleS[kb][wm * 64 + i * 16 + lanen];
            af[i] *= sh;
        }
#pragma unroll
        for (int j = 0; j < 8; j++) bf[j] = *(const half8*)&Bs[boff[j]];
#pragma unroll
        for (int i = 0; i < 4; i++)
#pragma unroll
            for (int j = 0; j < 8; j++)
                acc[i][j] = __builtin_amdgcn_mfma_f32_16x16x32_f16(bf[j], af[i], acc[i][j], 0, 0, 0);
        __syncthreads();
    }

    half_t* o = O16 + (long)z * SEQ * HID;
#pragma unroll
    for (int i = 0; i < 4; i++) {
        int qrl = wm * 64 + i * 16 + lanen;
        long qrow = m0 + qrl;
        float inv = invS[qrl];
#pragma unroll
        for (int j = 0; j < 8; j++) {
            long gn = h0 + wn * 128 + j * 16 + quad * 4;
            half4v hv;
#pragma unroll
            for (int r = 0; r < 4; r++) hv[r] = (half_t)(acc[i][j][r] * inv);
            *(half4v*)(o + qrow * HID + gn) = hv;
        }
    }
}

// ---------------- output projection, 128x128 tile, swapped ----------------
__global__ __launch_bounds__(256, 2) void oproj_k(
    const half_t* __restrict__ A, const half_t* __restrict__ Bw,
    float* __restrict__ Out, const float* __restrict__ bias)
{
    __shared__ alignas(16) half_t As[128 * 32];
    __shared__ alignas(16) half_t Bs[128 * 32];

    const int t    = threadIdx.x;
    const int lane = t & 63;
    const int wave = t >> 6;
    const int wm   = wave >> 1;
    const int wn   = wave & 1;
    const int lanen = lane & 15;
    const int quad  = lane >> 4;
    const long m0 = (long)blockIdx.x * 128;
    const long n0 = (long)blockIdx.y * 128;

    f32x4 acc[4][4];
#pragma unroll
    for (int i = 0; i < 4; i++)
#pragma unroll
        for (int j = 0; j < 4; j++)
            acc[i][j] = f32x4{0.f, 0.f, 0.f, 0.f};

    const int c0 = t, c1 = t + 256;
    const half_t* gA0 = A  + (m0 + (c0 >> 2)) * HID + (c0 & 3) * 8;
    const half_t* gA1 = A  + (m0 + (c1 >> 2)) * HID + (c1 & 3) * 8;
    const half_t* gB0 = Bw + (n0 + (c0 >> 2)) * HID + (c0 & 3) * 8;
    const half_t* gB1 = Bw + (n0 + (c1 >> 2)) * HID + (c1 & 3) * 8;
    half_t* lA0 = &As[c0 * 8];
    half_t* lA1 = &As[c1 * 8];
    half_t* lB0 = &Bs[c0 * 8];
    half_t* lB1 = &Bs[c1 * 8];

    int aoff[4], boff[4];
#pragma unroll
    for (int i = 0; i < 4; i++) aoff[i] = (wm * 64 + i * 16 + lanen) * 32 + quad * 8;
#pragma unroll
    for (int j = 0; j < 4; j++) boff[j] = (wn * 64 + j * 16 + lanen) * 32 + quad * 8;

    for (int k0 = 0; k0 < HID; k0 += 32) {
        __builtin_amdgcn_global_load_lds((gas_ptr)(gA0 + k0), (las_ptr)lA0, 16, 0, 0);
        __builtin_amdgcn_global_load_lds((gas_ptr)(gA1 + k0), (las_ptr)lA1, 16, 0, 0);
        __builtin_amdgcn_global_load_lds((gas_ptr)(gB0 + k0), (las_ptr)lB0, 16, 0, 0);
        __builtin_amdgcn_global_load_lds((gas_ptr)(gB1 + k0), (las_ptr)lB1, 16, 0, 0);
        __syncthreads();

        half8 af[4], bf[4];
#pragma unroll
        for (int i = 0; i < 4; i++) af[i] = *(const half8*)&As[aoff[i]];
#pragma unroll
        for (int j = 0; j < 4; j++) bf[j] = *(const half8*)&Bs[boff[j]];
#pragma unroll
        for (int i = 0; i < 4; i++)
#pragma unroll
            for (int j = 0; j < 4; j++)
                acc[i][j] = __builtin_amdgcn_mfma_f32_16x16x32_f16(bf[j], af[i], acc[i][j], 0, 0, 0);
        __syncthreads();
    }

    // swapped: lane row m = lanen-based, cols n = quad*4+r -> f32x4 stores
#pragma unroll
    for (int i = 0; i < 4; i++) {
        long mrow = m0 + wm * 64 + i * 16 + lanen;
#pragma unroll
        for (int j = 0; j < 4; j++) {
            long gn = n0 + wn * 64 + j * 16 + quad * 4;
            f32x4 bb = *(const f32x4*)&bias[gn];
            f32x4 v = acc[i][j];
            f32x4 ov;
#pragma unroll
            for (int r = 0; r < 4; r++) ov[r] = fmaxf(v[r] + bb[r], 0.f);
            *(f32x4*)&Out[mrow * DIN + gn] = ov;
        }
    }
}

// ---------------- host ----------------
extern "C" void kernel_launch(void* const* d_in, const int* in_sizes, int n_in,
                              void* d_out, int out_size, void* d_ws, size_t ws_size,
                              hipStream_t stream) {
    const float* h  = (const float*)d_in[0];
    const float* Wv = (const float*)d_in[1];
    const float* bv = (const float*)d_in[2];
    const float* Wk = (const float*)d_in[3];
    const float* bk = (const float*)d_in[4];
    const float* Wq = (const float*)d_in[5];
    const float* bq = (const float*)d_in[6];
    const float* Wo = (const float*)d_in[7];
    const float* bo = (const float*)d_in[8];

    uint8_t* ws = (uint8_t*)d_ws;
    size_t off = 0;
    auto alloc = [&](size_t bytes) { size_t o = off; off += (bytes + 255) & ~(size_t)255; return o; };

    half_t* W16   = (half_t*)(ws + alloc((size_t)3 * HID * DIN * 2)); // [Wv][Wk][Wq] = [1536][256]
    half_t* Wo16  = (half_t*)(ws + alloc((size_t)DIN * HID * 2));
    float*  biasq = (float*)(ws + alloc((size_t)3 * HID * 4));        // [bv][bk][bq]
    half_t* k16   = (half_t*)(ws + alloc((size_t)MTOT * HID * 2));
    half_t* q16   = (half_t*)(ws + alloc((size_t)MTOT * HID * 2));    // reused as O16 per group
    half_t* vT    = (half_t*)(ws + alloc((size_t)MTOT * HID * 2));    // [b][h][m]
    size_t h16_off = alloc((size_t)MTOT * DIN * 2);
    half_t* h16   = (half_t*)(ws + h16_off);
    half_t* O16 = q16;  // q dead after its group's se_k; O written strictly after

    // E + stats overlap the (dead-after-K1) h16 region onward; single group (GB=32)
    size_t s_avail = ws_size > h16_off ? ws_size - h16_off : 0;
    size_t per_batch = (size_t)SEQ * SEQ * 2 + 2 * 8 * SEQ * 4;
    int GB = (int)(s_avail / per_batch);
    if (GB > NB) GB = NB;
    if (GB < 1)  GB = 1;
    half_t* Ebuf  = (half_t*)(ws + h16_off);
    float*  Mstat = (float*)(ws + h16_off + (size_t)GB * SEQ * SEQ * 2);
    float*  Lstat = Mstat + (size_t)GB * 8 * SEQ;

    // K0: merged conversions
    cvt_all<<<dim3(8705), 256, 0, stream>>>(h, Wv, Wk, Wq, Wo, bv, bk, bq,
                                            h16, W16, Wo16, biasq);

    // K1: fused QKV projection (single GEMM, N=1536)
    qkv_k<<<dim3(MTOT / 128, 6), 256, 0, stream>>>(h16, W16, biasq, k16, q16, vT);

    for (int g0 = 0; g0 < NB; g0 += GB) {
        int gb = NB - g0 < GB ? NB - g0 : GB;
        se_k<<<dim3(SEQ / 128, SEQ / 256, gb), 256, 0, stream>>>(
            q16 + (size_t)g0 * SEQ * HID,
            k16 + (size_t)g0 * SEQ * HID,
            Ebuf, Mstat, Lstat);
        pv_k<<<dim3(SEQ / 128, HID / 256, gb), 256, 0, stream>>>(
            Ebuf, vT + (size_t)g0 * HID * SEQ,
            Mstat, Lstat,
            O16 + (size_t)g0 * SEQ * HID);
    }

    // K5: out = relu(O Wo^T + bo)
    oproj_k<<<dim3(MTOT / 128, DIN / 128), 256, 0, stream>>>(O16, Wo16, (float*)d_out, bo);

    (void)in_sizes; (void)n_in; (void)out_size;
}